// Round 2
// baseline (660.314 us; speedup 1.0000x reference)
//
#include <hip/hip_runtime.h>

// Problem constants (match reference)
#define D_   41
#define H_   159
#define W_   159
#define MD   20
#define MH   79
#define MW   79
#define CIN  32
#define COUT 64
#define BATCH 2

#define NTAP 27
// LDS weights: [tap][j4][co][4], u32 = bf16 ci-pair. Lane co reads 16B contiguous
// at ((t*4+j4)*64+co)*16 -> conflict-free ds_read_b128. 27*16*64*4 = 110,592 B.
#define WLDS (NTAP * 16 * 64)

// Block size for the two heavy kernels. 110.6KB LDS forces 1 block/CU either
// way; 768 threads = 12 waves/CU = 3 waves/SIMD -> VGPR cap 170 (vs 128 at
// 1024 threads). The event loops hold ~96 VGPRs of live arrays + state, which
// overflows a 128 cap (spill or A/B-stream serialization); 170 fits.
#define BLK   768
#define WPB   (BLK / 64)

typedef unsigned int u32;

static __device__ __forceinline__ u32 bf16_rn(float x) {
    u32 u = __float_as_uint(x);
    return (u + 0x7fffu + ((u >> 16) & 1u)) >> 16;   // round-to-nearest-even
}
static __device__ __forceinline__ float bf_lo(u32 p) { return __uint_as_float(p << 16); }
static __device__ __forceinline__ float bf_hi(u32 p) { return __uint_as_float(p & 0xffff0000u); }

// Pack w (fp32 [tap][ci][co]) -> [tap][j4][co][k] bf16-pairs (pair j=4*j4+k = ci 2j,2j+1).
__global__ void pack_kernel(const float* __restrict__ w1, const float* __restrict__ w2,
                            u32* __restrict__ w1p, u32* __restrict__ w2p) {
    int i = blockIdx.x * 256 + threadIdx.x;
    if (i >= WLDS) return;
    int k  = i & 3;
    int co = (i >> 2) & 63;
    int j4 = (i >> 8) & 3;
    int t  = i >> 10;
    int j  = j4 * 4 + k;
    int s0 = (t * 32 + 2 * j) * 64 + co;
    int s1 = (t * 32 + 2 * j + 1) * 64 + co;
    w1p[i] = bf16_rn(w1[s0]) | (bf16_rn(w1[s1]) << 16);
    w2p[i] = bf16_rn(w2[s0]) | (bf16_rn(w2[s1]) << 16);
}

// Scatter point index into dense idx grid (-1 = empty).
__global__ void scatter_idx_kernel(const int* __restrict__ coors,
                                   int* __restrict__ idx, int n) {
    int i = blockIdx.x * blockDim.x + threadIdx.x;
    if (i >= n) return;
    int4 c = ((const int4*)coors)[i];
    idx[((c.x * D_ + c.y) * H_ + c.z) * W_ + c.w] = i;
}

// Load one event's 16 weight pairs via 4 conflict-free ds_read_b128.
#define LOADW(dst, t)                                              \
    {                                                              \
        const uint4* wq = (const uint4*)lw + (t) * 256 + lane;     \
        uint4 q0 = wq[0], q1 = wq[64], q2 = wq[128], q3 = wq[192]; \
        dst[0] = q0.x;  dst[1] = q0.y;  dst[2] = q0.z;  dst[3] = q0.w;   \
        dst[4] = q1.x;  dst[5] = q1.y;  dst[6] = q1.z;  dst[7] = q1.w;   \
        dst[8] = q2.x;  dst[9] = q2.y;  dst[10] = q2.z; dst[11] = q2.w;  \
        dst[12] = q3.x; dst[13] = q3.y; dst[14] = q3.z; dst[15] = q3.w;  \
    }

// mid: one wave per voxel PAIR per iteration; probes prefetched; two event
// streams interleaved; w1 in LDS read as b128.
__global__ __launch_bounds__(BLK) void mid_kernel(const float* __restrict__ feat,
                                                  const int* __restrict__ idx,
                                                  const u32* __restrict__ w1p,
                                                  float* __restrict__ mid) {
    __shared__ u32 lw[WLDS];
    for (int i = threadIdx.x; i < WLDS; i += BLK) lw[i] = w1p[i];
    __syncthreads();

    const int NV = BATCH * MD * MH * MW;
    int lane = threadIdx.x & 63;
    int wid  = threadIdx.x >> 6;
    int nw   = gridDim.x * WPB;
    int gw   = blockIdx.x * WPB + wid;
    int per  = (NV + nw - 1) / nw;
    int v0   = gw * per;
    int v1   = v0 + per; if (v1 > NV) v1 = NV;

    int l  = lane < NTAP ? lane : NTAP - 1;
    int kz = l / 9, kr = l % 9, ky = kr / 3, kx = kr % 3;

    auto probe = [&](int v) -> int {
        if (v >= v1 || lane >= NTAP) return -1;
        int xo = v % MW; int t0 = v / MW;
        int yo = t0 % MH; t0 /= MH;
        int zo = t0 % MD; int b = t0 / MD;
        return idx[((b * D_ + 2 * zo + kz) * H_ + 2 * yo + ky) * W_ + 2 * xo + kx];
    };

    int pA = probe(v0), pB = probe(v0 + 1);
    for (int v = v0; v < v1; v += 2) {
        int cA = pA, cB = pB;
        pA = probe(v + 2);            // prefetch next pair's probes
        pB = probe(v + 3);
        unsigned long long mA = __ballot(cA >= 0);
        unsigned long long mB = __ballot(cB >= 0);

        float a0 = 0.f, a1 = 0.f, b0 = 0.f, b1 = 0.f;
        while (mA | mB) {
            bool hA = mA != 0, hB = mB != 0;   // wave-uniform
            float4 fav[8], fbv[8];
            u32 wav[16], wbv[16];
            if (hA) {
                int t = (int)__builtin_ctzll(mA); mA &= mA - 1;
                int pp = __shfl(cA, t);
                const float4* f4 = (const float4*)(feat + (size_t)pp * CIN);
                #pragma unroll
                for (int q = 0; q < 8; ++q) fav[q] = f4[q];
                LOADW(wav, t)
            }
            if (hB) {
                int t = (int)__builtin_ctzll(mB); mB &= mB - 1;
                int pp = __shfl(cB, t);
                const float4* f4 = (const float4*)(feat + (size_t)pp * CIN);
                #pragma unroll
                for (int q = 0; q < 8; ++q) fbv[q] = f4[q];
                LOADW(wbv, t)
            }
            if (hA) {
                #pragma unroll
                for (int q = 0; q < 8; ++q) {
                    a0 = fmaf(fav[q].x, bf_lo(wav[2 * q + 0]), a0);
                    a1 = fmaf(fav[q].y, bf_hi(wav[2 * q + 0]), a1);
                    a0 = fmaf(fav[q].z, bf_lo(wav[2 * q + 1]), a0);
                    a1 = fmaf(fav[q].w, bf_hi(wav[2 * q + 1]), a1);
                }
            }
            if (hB) {
                #pragma unroll
                for (int q = 0; q < 8; ++q) {
                    b0 = fmaf(fbv[q].x, bf_lo(wbv[2 * q + 0]), b0);
                    b1 = fmaf(fbv[q].y, bf_hi(wbv[2 * q + 0]), b1);
                    b0 = fmaf(fbv[q].z, bf_lo(wbv[2 * q + 1]), b0);
                    b1 = fmaf(fbv[q].w, bf_hi(wbv[2 * q + 1]), b1);
                }
            }
        }
        mid[(size_t)v * COUT + lane] = a0 + a1;
        if (v + 1 < v1) mid[(size_t)(v + 1) * COUT + lane] = b0 + b1;
    }
}

// Statically-unrolled butterfly reduce-scatter step (no dynamic indexing -> no spill).
#define BSTEP(MK, HALF)                                            \
    {                                                              \
        bool up = (lane & MK) != 0;                                \
        _Pragma("unroll")                                          \
        for (int k = 0; k < HALF; ++k) {                           \
            float send = up ? acc[k] : acc[k + HALF];              \
            float keep = up ? acc[k + HALF] : acc[k];              \
            acc[k] = keep + __shfl_xor(send, MK, 64);              \
        }                                                          \
    }

// out: one wave per point; coors prefetched; events in PAIRS; w2 in LDS (b128).
__global__ __launch_bounds__(BLK) void out_kernel(const int* __restrict__ coors,
                                                  const float* __restrict__ mid,
                                                  const u32* __restrict__ w2p,
                                                  float* __restrict__ out, int n) {
    __shared__ u32 lw[WLDS];
    for (int i = threadIdx.x; i < WLDS; i += BLK) lw[i] = w2p[i];
    __syncthreads();

    int lane = threadIdx.x & 63;
    int wid  = threadIdx.x >> 6;
    int nw   = gridDim.x * WPB;
    int gw   = blockIdx.x * WPB + wid;
    int per  = (n + nw - 1) / nw;
    int i0   = gw * per;
    int i1   = i0 + per; if (i1 > n) i1 = n;

    int l  = lane < NTAP ? lane : NTAP - 1;
    int kz = l / 9, kr = l % 9, ky = kr / 3, kx = kr % 3;

    const int4* cvec = (const int4*)coors;
    int4 nc = make_int4(0, 0, 0, 0);
    if (i0 < i1) nc = cvec[i0];

    for (int i = i0; i < i1; ++i) {
        int4 c = nc;
        if (i + 1 < i1) nc = cvec[i + 1];   // prefetch next point
        int b = c.x, z = c.y, y = c.z, x = c.w;

        int zr = z - kz, yr = y - ky, xr = x - kx;
        bool ok = (lane < NTAP) &&
                  zr >= 0 && !(zr & 1) && (zr >> 1) < MD &&
                  yr >= 0 && !(yr & 1) && (yr >> 1) < MH &&
                  xr >= 0 && !(xr & 1) && (xr >> 1) < MW;
        int vv = ok ? ((b * MD + (zr >> 1)) * MH + (yr >> 1)) * MW + (xr >> 1) : -1;
        unsigned long long m = __ballot(ok);

        float acc[CIN];
        #pragma unroll
        for (int ci = 0; ci < CIN; ++ci) acc[ci] = 0.f;

        while (m) {
            int t0 = (int)__builtin_ctzll(m); m &= m - 1;
            bool h1 = (m != 0);               // wave-uniform
            int t1 = 0;
            if (h1) { t1 = (int)__builtin_ctzll(m); m &= m - 1; }

            int ve0 = __shfl(vv, t0);
            float mr0 = mid[(size_t)ve0 * COUT + lane];
            u32 wv0[16];
            LOADW(wv0, t0)

            float mr1 = 0.f; u32 wv1[16];
            if (h1) {
                int ve1 = __shfl(vv, t1);
                mr1 = mid[(size_t)ve1 * COUT + lane];
                LOADW(wv1, t1)
            }

            #pragma unroll
            for (int j = 0; j < 16; ++j) {
                acc[2 * j + 0] = fmaf(mr0, bf_lo(wv0[j]), acc[2 * j + 0]);
                acc[2 * j + 1] = fmaf(mr0, bf_hi(wv0[j]), acc[2 * j + 1]);
            }
            if (h1) {
                #pragma unroll
                for (int j = 0; j < 16; ++j) {
                    acc[2 * j + 0] = fmaf(mr1, bf_lo(wv1[j]), acc[2 * j + 0]);
                    acc[2 * j + 1] = fmaf(mr1, bf_hi(wv1[j]), acc[2 * j + 1]);
                }
            }
        }

        // Reduce-scatter 32 ci over 64 lanes (co): 5 static butterfly steps.
        BSTEP(32, 16)
        BSTEP(16, 8)
        BSTEP(8, 4)
        BSTEP(4, 2)
        BSTEP(2, 1)
        float s = acc[0] + __shfl_xor(acc[0], 1, 64);
        if (!(lane & 1)) {
            int ci = lane >> 1;
            out[((size_t)(b * CIN + ci) * D_ + z) * (H_ * W_) + (size_t)y * W_ + x] = s;
        }
    }
}

extern "C" void kernel_launch(void* const* d_in, const int* in_sizes, int n_in,
                              void* d_out, int out_size, void* d_ws, size_t ws_size,
                              hipStream_t stream) {
    const float* feat  = (const float*)d_in[0];
    const int*   coors = (const int*)d_in[1];
    const float* w1    = (const float*)d_in[3];
    const float* w2    = (const float*)d_in[4];
    float*       out   = (float*)d_out;

    int n = in_sizes[0] / CIN;   // 150000 points total

    // Workspace: [idx 8.3MB][mid 64MB][w1p 110.6KB][w2p 110.6KB]
    int*   idx      = (int*)d_ws;
    size_t idxBytes = (size_t)BATCH * D_ * H_ * W_ * sizeof(int);
    size_t midOff   = (idxBytes + 255) & ~(size_t)255;
    float* mid      = (float*)((char*)d_ws + midOff);
    size_t wOff     = midOff + (size_t)BATCH * MD * MH * MW * COUT * sizeof(float);
    wOff            = (wOff + 255) & ~(size_t)255;
    u32*   w1p      = (u32*)((char*)d_ws + wOff);
    u32*   w2p      = w1p + WLDS;

    // Output: exactly B*CIN*D*H*W floats. (The 1.06GB fills visible in rocprof
    // are harness-side poison fills, not this memset.)
    size_t outBytes = (size_t)BATCH * CIN * D_ * H_ * W_ * sizeof(float);

    hipMemsetAsync(idx, 0xFF, idxBytes, stream);      // idx = -1
    hipMemsetAsync(d_out, 0, outBytes, stream);       // dense zeros

    pack_kernel<<<(WLDS + 255) / 256, 256, 0, stream>>>(w1, w2, w1p, w2p);
    scatter_idx_kernel<<<(n + 255) / 256, 256, 0, stream>>>(coors, idx, n);

    mid_kernel<<<256, BLK, 0, stream>>>(feat, idx, w1p, mid);
    out_kernel<<<256, BLK, 0, stream>>>(coors, mid, w2p, out, n);
}

// Round 4
// 634.590 us; speedup vs baseline: 1.0405x; 1.0405x over previous
//
#include <hip/hip_runtime.h>

// Problem constants (match reference)
#define D_   41
#define H_   159
#define W_   159
#define MD   20
#define MH   79
#define MW   79
#define CIN  32
#define COUT 64
#define BATCH 2

#define NTAP 27
// LDS weights: [tap][j4][co][4], u32 = bf16 ci-pair. Lane co reads 16B contiguous
// at ((t*4+j4)*64+co)*16 -> conflict-free ds_read_b128. 27*16*64*4 = 110,592 B.
#define WLDS (NTAP * 16 * 64)

// 1024 thr/block: 110.6KB LDS forces 1 block/CU regardless; 16 waves/CU
// maximizes TLP. (768-thread experiment cost +30us -> latency-bound, reverted.)
#define BLK   1024
#define WPB   (BLK / 64)

typedef unsigned int u32;
// Native clang vector for nontemporal stores (__builtin_nontemporal_store
// rejects HIP_vector_type float4 -- needs a real vector type).
typedef float vfloat4 __attribute__((ext_vector_type(4)));

static __device__ __forceinline__ u32 bf16_rn(float x) {
    u32 u = __float_as_uint(x);
    return (u + 0x7fffu + ((u >> 16) & 1u)) >> 16;   // round-to-nearest-even
}
static __device__ __forceinline__ float bf_lo(u32 p) { return __uint_as_float(p << 16); }
static __device__ __forceinline__ float bf_hi(u32 p) { return __uint_as_float(p & 0xffff0000u); }

// Pack w (fp32 [tap][ci][co]) -> [tap][j4][co][k] bf16-pairs (pair j=4*j4+k = ci 2j,2j+1).
__global__ void pack_kernel(const float* __restrict__ w1, const float* __restrict__ w2,
                            u32* __restrict__ w1p, u32* __restrict__ w2p) {
    int i = blockIdx.x * 256 + threadIdx.x;
    if (i >= WLDS) return;
    int k  = i & 3;
    int co = (i >> 2) & 63;
    int j4 = (i >> 8) & 3;
    int t  = i >> 10;
    int j  = j4 * 4 + k;
    int s0 = (t * 32 + 2 * j) * 64 + co;
    int s1 = (t * 32 + 2 * j + 1) * 64 + co;
    w1p[i] = bf16_rn(w1[s0]) | (bf16_rn(w1[s1]) << 16);
    w2p[i] = bf16_rn(w2[s0]) | (bf16_rn(w2[s1]) << 16);
}

// Scatter point index into dense idx grid (-1 = empty).
__global__ void scatter_idx_kernel(const int* __restrict__ coors,
                                   int* __restrict__ idx, int n) {
    int i = blockIdx.x * blockDim.x + threadIdx.x;
    if (i >= n) return;
    int4 c = ((const int4*)coors)[i];
    idx[((c.x * D_ + c.y) * H_ + c.z) * W_ + c.w] = i;
}

// Load one event's 16 weight pairs via 4 conflict-free ds_read_b128.
#define LOADW(dst, t)                                              \
    {                                                              \
        const uint4* wq = (const uint4*)lw + (t) * 256 + lane;     \
        uint4 q0 = wq[0], q1 = wq[64], q2 = wq[128], q3 = wq[192]; \
        dst[0] = q0.x;  dst[1] = q0.y;  dst[2] = q0.z;  dst[3] = q0.w;   \
        dst[4] = q1.x;  dst[5] = q1.y;  dst[6] = q1.z;  dst[7] = q1.w;   \
        dst[8] = q2.x;  dst[9] = q2.y;  dst[10] = q2.z; dst[11] = q2.w;  \
        dst[12] = q3.x; dst[13] = q3.y; dst[14] = q3.z; dst[15] = q3.w;  \
    }

// mid: one wave per voxel PAIR per iteration; probes prefetched; two event
// streams interleaved; w1 in LDS read as b128. Also zero-fills the dense
// output (overlaps the fill's ~42us of HBM-write time with mid's
// latency-bound compute; replaces a ~54us serialized memset).
__global__ __launch_bounds__(BLK) void mid_kernel(const float* __restrict__ feat,
                                                  const int* __restrict__ idx,
                                                  const u32* __restrict__ w1p,
                                                  float* __restrict__ mid,
                                                  float* __restrict__ outz) {
    __shared__ u32 lw[WLDS];
    for (int i = threadIdx.x; i < WLDS; i += BLK) lw[i] = w1p[i];

    // Grid-stride nontemporal zero of the dense output (16,584,336 float4s;
    // ~63 stores/thread). Fire-and-forget: drains under the event loop.
    {
        const int NOUT4 = (BATCH * CIN * D_ * H_ * W_) / 4;
        vfloat4* o4 = (vfloat4*)outz;
        vfloat4 z4 = (vfloat4){0.f, 0.f, 0.f, 0.f};
        for (int i = blockIdx.x * BLK + threadIdx.x; i < NOUT4; i += 256 * BLK)
            __builtin_nontemporal_store(z4, o4 + i);
    }
    __syncthreads();

    const int NV = BATCH * MD * MH * MW;
    int lane = threadIdx.x & 63;
    int wid  = threadIdx.x >> 6;
    int nw   = gridDim.x * WPB;
    int gw   = blockIdx.x * WPB + wid;
    int per  = (NV + nw - 1) / nw;
    int v0   = gw * per;
    int v1   = v0 + per; if (v1 > NV) v1 = NV;

    int l  = lane < NTAP ? lane : NTAP - 1;
    int kz = l / 9, kr = l % 9, ky = kr / 3, kx = kr % 3;

    auto probe = [&](int v) -> int {
        if (v >= v1 || lane >= NTAP) return -1;
        int xo = v % MW; int t0 = v / MW;
        int yo = t0 % MH; t0 /= MH;
        int zo = t0 % MD; int b = t0 / MD;
        return idx[((b * D_ + 2 * zo + kz) * H_ + 2 * yo + ky) * W_ + 2 * xo + kx];
    };

    int pA = probe(v0), pB = probe(v0 + 1);
    for (int v = v0; v < v1; v += 2) {
        int cA = pA, cB = pB;
        pA = probe(v + 2);            // prefetch next pair's probes
        pB = probe(v + 3);
        unsigned long long mA = __ballot(cA >= 0);
        unsigned long long mB = __ballot(cB >= 0);

        float a0 = 0.f, a1 = 0.f, b0 = 0.f, b1 = 0.f;
        while (mA | mB) {
            bool hA = mA != 0, hB = mB != 0;   // wave-uniform
            float4 fav[8], fbv[8];
            u32 wav[16], wbv[16];
            if (hA) {
                int t = (int)__builtin_ctzll(mA); mA &= mA - 1;
                int pp = __shfl(cA, t);
                const float4* f4 = (const float4*)(feat + (size_t)pp * CIN);
                #pragma unroll
                for (int q = 0; q < 8; ++q) fav[q] = f4[q];
                LOADW(wav, t)
            }
            if (hB) {
                int t = (int)__builtin_ctzll(mB); mB &= mB - 1;
                int pp = __shfl(cB, t);
                const float4* f4 = (const float4*)(feat + (size_t)pp * CIN);
                #pragma unroll
                for (int q = 0; q < 8; ++q) fbv[q] = f4[q];
                LOADW(wbv, t)
            }
            if (hA) {
                #pragma unroll
                for (int q = 0; q < 8; ++q) {
                    a0 = fmaf(fav[q].x, bf_lo(wav[2 * q + 0]), a0);
                    a1 = fmaf(fav[q].y, bf_hi(wav[2 * q + 0]), a1);
                    a0 = fmaf(fav[q].z, bf_lo(wav[2 * q + 1]), a0);
                    a1 = fmaf(fav[q].w, bf_hi(wav[2 * q + 1]), a1);
                }
            }
            if (hB) {
                #pragma unroll
                for (int q = 0; q < 8; ++q) {
                    b0 = fmaf(fbv[q].x, bf_lo(wbv[2 * q + 0]), b0);
                    b1 = fmaf(fbv[q].y, bf_hi(wbv[2 * q + 0]), b1);
                    b0 = fmaf(fbv[q].z, bf_lo(wbv[2 * q + 1]), b0);
                    b1 = fmaf(fbv[q].w, bf_hi(wbv[2 * q + 1]), b1);
                }
            }
        }
        mid[(size_t)v * COUT + lane] = a0 + a1;
        if (v + 1 < v1) mid[(size_t)(v + 1) * COUT + lane] = b0 + b1;
    }
}

// Statically-unrolled butterfly reduce-scatter step (no dynamic indexing -> no spill).
#define BSTEP(MK, HALF)                                            \
    {                                                              \
        bool up = (lane & MK) != 0;                                \
        _Pragma("unroll")                                          \
        for (int k = 0; k < HALF; ++k) {                           \
            float send = up ? acc[k] : acc[k + HALF];              \
            float keep = up ? acc[k + HALF] : acc[k];              \
            acc[k] = keep + __shfl_xor(send, MK, 64);              \
        }                                                          \
    }

// out: one wave per point; coors prefetched; events in PAIRS; w2 in LDS (b128).
__global__ __launch_bounds__(BLK) void out_kernel(const int* __restrict__ coors,
                                                  const float* __restrict__ mid,
                                                  const u32* __restrict__ w2p,
                                                  float* __restrict__ out, int n) {
    __shared__ u32 lw[WLDS];
    for (int i = threadIdx.x; i < WLDS; i += BLK) lw[i] = w2p[i];
    __syncthreads();

    int lane = threadIdx.x & 63;
    int wid  = threadIdx.x >> 6;
    int nw   = gridDim.x * WPB;
    int gw   = blockIdx.x * WPB + wid;
    int per  = (n + nw - 1) / nw;
    int i0   = gw * per;
    int i1   = i0 + per; if (i1 > n) i1 = n;

    int l  = lane < NTAP ? lane : NTAP - 1;
    int kz = l / 9, kr = l % 9, ky = kr / 3, kx = kr % 3;

    const int4* cvec = (const int4*)coors;
    int4 nc = make_int4(0, 0, 0, 0);
    if (i0 < i1) nc = cvec[i0];

    for (int i = i0; i < i1; ++i) {
        int4 c = nc;
        if (i + 1 < i1) nc = cvec[i + 1];   // prefetch next point
        int b = c.x, z = c.y, y = c.z, x = c.w;

        int zr = z - kz, yr = y - ky, xr = x - kx;
        bool ok = (lane < NTAP) &&
                  zr >= 0 && !(zr & 1) && (zr >> 1) < MD &&
                  yr >= 0 && !(yr & 1) && (yr >> 1) < MH &&
                  xr >= 0 && !(xr & 1) && (xr >> 1) < MW;
        int vv = ok ? ((b * MD + (zr >> 1)) * MH + (yr >> 1)) * MW + (xr >> 1) : -1;
        unsigned long long m = __ballot(ok);

        float acc[CIN];
        #pragma unroll
        for (int ci = 0; ci < CIN; ++ci) acc[ci] = 0.f;

        while (m) {
            int t0 = (int)__builtin_ctzll(m); m &= m - 1;
            bool h1 = (m != 0);               // wave-uniform
            int t1 = 0;
            if (h1) { t1 = (int)__builtin_ctzll(m); m &= m - 1; }

            int ve0 = __shfl(vv, t0);
            float mr0 = mid[(size_t)ve0 * COUT + lane];
            u32 wv0[16];
            LOADW(wv0, t0)

            float mr1 = 0.f; u32 wv1[16];
            if (h1) {
                int ve1 = __shfl(vv, t1);
                mr1 = mid[(size_t)ve1 * COUT + lane];
                LOADW(wv1, t1)
            }

            #pragma unroll
            for (int j = 0; j < 16; ++j) {
                acc[2 * j + 0] = fmaf(mr0, bf_lo(wv0[j]), acc[2 * j + 0]);
                acc[2 * j + 1] = fmaf(mr0, bf_hi(wv0[j]), acc[2 * j + 1]);
            }
            if (h1) {
                #pragma unroll
                for (int j = 0; j < 16; ++j) {
                    acc[2 * j + 0] = fmaf(mr1, bf_lo(wv1[j]), acc[2 * j + 0]);
                    acc[2 * j + 1] = fmaf(mr1, bf_hi(wv1[j]), acc[2 * j + 1]);
                }
            }
        }

        // Reduce-scatter 32 ci over 64 lanes (co): 5 static butterfly steps.
        BSTEP(32, 16)
        BSTEP(16, 8)
        BSTEP(8, 4)
        BSTEP(4, 2)
        BSTEP(2, 1)
        float s = acc[0] + __shfl_xor(acc[0], 1, 64);
        if (!(lane & 1)) {
            int ci = lane >> 1;
            out[((size_t)(b * CIN + ci) * D_ + z) * (H_ * W_) + (size_t)y * W_ + x] = s;
        }
    }
}

extern "C" void kernel_launch(void* const* d_in, const int* in_sizes, int n_in,
                              void* d_out, int out_size, void* d_ws, size_t ws_size,
                              hipStream_t stream) {
    const float* feat  = (const float*)d_in[0];
    const int*   coors = (const int*)d_in[1];
    const float* w1    = (const float*)d_in[3];
    const float* w2    = (const float*)d_in[4];
    float*       out   = (float*)d_out;

    int n = in_sizes[0] / CIN;   // 150000 points total

    // Workspace: [idx 8.3MB][mid 64MB][w1p 110.6KB][w2p 110.6KB]
    int*   idx      = (int*)d_ws;
    size_t idxBytes = (size_t)BATCH * D_ * H_ * W_ * sizeof(int);
    size_t midOff   = (idxBytes + 255) & ~(size_t)255;
    float* mid      = (float*)((char*)d_ws + midOff);
    size_t wOff     = midOff + (size_t)BATCH * MD * MH * MW * COUT * sizeof(float);
    wOff            = (wOff + 255) & ~(size_t)255;
    u32*   w1p      = (u32*)((char*)d_ws + wOff);
    u32*   w2p      = w1p + WLDS;

    (void)hipMemsetAsync(idx, 0xFF, idxBytes, stream);   // idx = -1
    // NOTE: no output memset -- mid_kernel zero-fills `out` internally,
    // hiding the 265MB fill under its latency-bound event loop. The 1.06GB
    // fills in rocprof are harness-side poison fills (survived two memset
    // edits unchanged), not ours.

    pack_kernel<<<(WLDS + 255) / 256, 256, 0, stream>>>(w1, w2, w1p, w2p);
    scatter_idx_kernel<<<(n + 255) / 256, 256, 0, stream>>>(coors, idx, n);

    mid_kernel<<<256, BLK, 0, stream>>>(feat, idx, w1p, mid, out);
    out_kernel<<<256, BLK, 0, stream>>>(coors, mid, w2p, out, n);
}

// Round 5
// 621.470 us; speedup vs baseline: 1.0625x; 1.0211x over previous
//
#include <hip/hip_runtime.h>

// Problem constants (match reference)
#define D_   41
#define H_   159
#define W_   159
#define MD   20
#define MH   79
#define MW   79
#define CIN  32
#define COUT 64
#define BATCH 2

#define NTAP 27
// LDS weights: [tap][j4][co][4], u32 = bf16 ci-pair. Lane co reads 16B contiguous
// at ((t*4+j4)*64+co)*16 -> conflict-free ds_read_b128. 27*16*64*4 = 110,592 B.
#define WLDS (NTAP * 16 * 64)

// 1024 thr/block: 110.6KB LDS forces 1 block/CU regardless; 16 waves/CU
// maximizes TLP. (768-thread experiment cost +30us -> latency-bound, reverted.)
#define BLK   1024
#define WPB   (BLK / 64)

typedef unsigned int u32;

static __device__ __forceinline__ u32 bf16_rn(float x) {
    u32 u = __float_as_uint(x);
    return (u + 0x7fffu + ((u >> 16) & 1u)) >> 16;   // round-to-nearest-even
}
static __device__ __forceinline__ float bf_lo(u32 p) { return __uint_as_float(p << 16); }
static __device__ __forceinline__ float bf_hi(u32 p) { return __uint_as_float(p & 0xffff0000u); }

// Pack w (fp32 [tap][ci][co]) -> [tap][j4][co][k] bf16-pairs (pair j=4*j4+k = ci 2j,2j+1).
__global__ void pack_kernel(const float* __restrict__ w1, const float* __restrict__ w2,
                            u32* __restrict__ w1p, u32* __restrict__ w2p) {
    int i = blockIdx.x * 256 + threadIdx.x;
    if (i >= WLDS) return;
    int k  = i & 3;
    int co = (i >> 2) & 63;
    int j4 = (i >> 8) & 3;
    int t  = i >> 10;
    int j  = j4 * 4 + k;
    int s0 = (t * 32 + 2 * j) * 64 + co;
    int s1 = (t * 32 + 2 * j + 1) * 64 + co;
    w1p[i] = bf16_rn(w1[s0]) | (bf16_rn(w1[s1]) << 16);
    w2p[i] = bf16_rn(w2[s0]) | (bf16_rn(w2[s1]) << 16);
}

// Scatter point index into dense idx grid (-1 = empty).
__global__ void scatter_idx_kernel(const int* __restrict__ coors,
                                   int* __restrict__ idx, int n) {
    int i = blockIdx.x * blockDim.x + threadIdx.x;
    if (i >= n) return;
    int4 c = ((const int4*)coors)[i];
    idx[((c.x * D_ + c.y) * H_ + c.z) * W_ + c.w] = i;
}

// Load one event's 16 weight pairs via 4 conflict-free ds_read_b128.
#define LOADW(dst, t)                                              \
    {                                                              \
        const uint4* wq = (const uint4*)lw + (t) * 256 + lane;     \
        uint4 q0 = wq[0], q1 = wq[64], q2 = wq[128], q3 = wq[192]; \
        dst[0] = q0.x;  dst[1] = q0.y;  dst[2] = q0.z;  dst[3] = q0.w;   \
        dst[4] = q1.x;  dst[5] = q1.y;  dst[6] = q1.z;  dst[7] = q1.w;   \
        dst[8] = q2.x;  dst[9] = q2.y;  dst[10] = q2.z; dst[11] = q2.w;  \
        dst[12] = q3.x; dst[13] = q3.y; dst[14] = q3.z; dst[15] = q3.w;  \
    }

// mid: one wave per voxel PAIR per iteration; probes prefetched; two event
// streams interleaved; w1 in LDS read as b128.
__global__ __launch_bounds__(BLK) void mid_kernel(const float* __restrict__ feat,
                                                  const int* __restrict__ idx,
                                                  const u32* __restrict__ w1p,
                                                  float* __restrict__ mid) {
    __shared__ u32 lw[WLDS];
    for (int i = threadIdx.x; i < WLDS; i += BLK) lw[i] = w1p[i];
    __syncthreads();

    const int NV = BATCH * MD * MH * MW;
    int lane = threadIdx.x & 63;
    int wid  = threadIdx.x >> 6;
    int nw   = gridDim.x * WPB;
    int gw   = blockIdx.x * WPB + wid;
    int per  = (NV + nw - 1) / nw;
    int v0   = gw * per;
    int v1   = v0 + per; if (v1 > NV) v1 = NV;

    int l  = lane < NTAP ? lane : NTAP - 1;
    int kz = l / 9, kr = l % 9, ky = kr / 3, kx = kr % 3;

    auto probe = [&](int v) -> int {
        if (v >= v1 || lane >= NTAP) return -1;
        int xo = v % MW; int t0 = v / MW;
        int yo = t0 % MH; t0 /= MH;
        int zo = t0 % MD; int b = t0 / MD;
        return idx[((b * D_ + 2 * zo + kz) * H_ + 2 * yo + ky) * W_ + 2 * xo + kx];
    };

    int pA = probe(v0), pB = probe(v0 + 1);
    for (int v = v0; v < v1; v += 2) {
        int cA = pA, cB = pB;
        pA = probe(v + 2);            // prefetch next pair's probes
        pB = probe(v + 3);
        unsigned long long mA = __ballot(cA >= 0);
        unsigned long long mB = __ballot(cB >= 0);

        float a0 = 0.f, a1 = 0.f, b0 = 0.f, b1 = 0.f;
        while (mA | mB) {
            bool hA = mA != 0, hB = mB != 0;   // wave-uniform
            float4 fav[8], fbv[8];
            u32 wav[16], wbv[16];
            if (hA) {
                int t = (int)__builtin_ctzll(mA); mA &= mA - 1;
                int pp = __shfl(cA, t);
                const float4* f4 = (const float4*)(feat + (size_t)pp * CIN);
                #pragma unroll
                for (int q = 0; q < 8; ++q) fav[q] = f4[q];
                LOADW(wav, t)
            }
            if (hB) {
                int t = (int)__builtin_ctzll(mB); mB &= mB - 1;
                int pp = __shfl(cB, t);
                const float4* f4 = (const float4*)(feat + (size_t)pp * CIN);
                #pragma unroll
                for (int q = 0; q < 8; ++q) fbv[q] = f4[q];
                LOADW(wbv, t)
            }
            if (hA) {
                #pragma unroll
                for (int q = 0; q < 8; ++q) {
                    a0 = fmaf(fav[q].x, bf_lo(wav[2 * q + 0]), a0);
                    a1 = fmaf(fav[q].y, bf_hi(wav[2 * q + 0]), a1);
                    a0 = fmaf(fav[q].z, bf_lo(wav[2 * q + 1]), a0);
                    a1 = fmaf(fav[q].w, bf_hi(wav[2 * q + 1]), a1);
                }
            }
            if (hB) {
                #pragma unroll
                for (int q = 0; q < 8; ++q) {
                    b0 = fmaf(fbv[q].x, bf_lo(wbv[2 * q + 0]), b0);
                    b1 = fmaf(fbv[q].y, bf_hi(wbv[2 * q + 0]), b1);
                    b0 = fmaf(fbv[q].z, bf_lo(wbv[2 * q + 1]), b0);
                    b1 = fmaf(fbv[q].w, bf_hi(wbv[2 * q + 1]), b1);
                }
            }
        }
        mid[(size_t)v * COUT + lane] = a0 + a1;
        if (v + 1 < v1) mid[(size_t)(v + 1) * COUT + lane] = b0 + b1;
    }
}

// Statically-unrolled butterfly reduce-scatter step (no dynamic indexing -> no spill).
#define BSTEP(MK, HALF)                                            \
    {                                                              \
        bool up = (lane & MK) != 0;                                \
        _Pragma("unroll")                                          \
        for (int k = 0; k < HALF; ++k) {                           \
            float send = up ? acc[k] : acc[k + HALF];              \
            float keep = up ? acc[k + HALF] : acc[k];              \
            acc[k] = keep + __shfl_xor(send, MK, 64);              \
        }                                                          \
    }

// out: one wave per point; coors prefetched; events in PAIRS; w2 in LDS (b128).
// Writes a COMPACT [n][32] row per point (coalesced 128B) instead of 32
// plane-strided 4B scatters into the dense output (which cost ~300MB of
// 64B-sector write amplification). A separate expand_kernel materializes
// the dense output with full-line coalesced stores.
__global__ __launch_bounds__(BLK) void out_kernel(const int* __restrict__ coors,
                                                  const float* __restrict__ mid,
                                                  const u32* __restrict__ w2p,
                                                  float* __restrict__ compact, int n) {
    __shared__ u32 lw[WLDS];
    for (int i = threadIdx.x; i < WLDS; i += BLK) lw[i] = w2p[i];
    __syncthreads();

    int lane = threadIdx.x & 63;
    int wid  = threadIdx.x >> 6;
    int nw   = gridDim.x * WPB;
    int gw   = blockIdx.x * WPB + wid;
    int per  = (n + nw - 1) / nw;
    int i0   = gw * per;
    int i1   = i0 + per; if (i1 > n) i1 = n;

    int l  = lane < NTAP ? lane : NTAP - 1;
    int kz = l / 9, kr = l % 9, ky = kr / 3, kx = kr % 3;

    const int4* cvec = (const int4*)coors;
    int4 nc = make_int4(0, 0, 0, 0);
    if (i0 < i1) nc = cvec[i0];

    for (int i = i0; i < i1; ++i) {
        int4 c = nc;
        if (i + 1 < i1) nc = cvec[i + 1];   // prefetch next point
        int b = c.x, z = c.y, y = c.z, x = c.w;

        int zr = z - kz, yr = y - ky, xr = x - kx;
        bool ok = (lane < NTAP) &&
                  zr >= 0 && !(zr & 1) && (zr >> 1) < MD &&
                  yr >= 0 && !(yr & 1) && (yr >> 1) < MH &&
                  xr >= 0 && !(xr & 1) && (xr >> 1) < MW;
        int vv = ok ? ((b * MD + (zr >> 1)) * MH + (yr >> 1)) * MW + (xr >> 1) : -1;
        unsigned long long m = __ballot(ok);

        float acc[CIN];
        #pragma unroll
        for (int ci = 0; ci < CIN; ++ci) acc[ci] = 0.f;

        while (m) {
            int t0 = (int)__builtin_ctzll(m); m &= m - 1;
            bool h1 = (m != 0);               // wave-uniform
            int t1 = 0;
            if (h1) { t1 = (int)__builtin_ctzll(m); m &= m - 1; }

            int ve0 = __shfl(vv, t0);
            float mr0 = mid[(size_t)ve0 * COUT + lane];
            u32 wv0[16];
            LOADW(wv0, t0)

            float mr1 = 0.f; u32 wv1[16];
            if (h1) {
                int ve1 = __shfl(vv, t1);
                mr1 = mid[(size_t)ve1 * COUT + lane];
                LOADW(wv1, t1)
            }

            #pragma unroll
            for (int j = 0; j < 16; ++j) {
                acc[2 * j + 0] = fmaf(mr0, bf_lo(wv0[j]), acc[2 * j + 0]);
                acc[2 * j + 1] = fmaf(mr0, bf_hi(wv0[j]), acc[2 * j + 1]);
            }
            if (h1) {
                #pragma unroll
                for (int j = 0; j < 16; ++j) {
                    acc[2 * j + 0] = fmaf(mr1, bf_lo(wv1[j]), acc[2 * j + 0]);
                    acc[2 * j + 1] = fmaf(mr1, bf_hi(wv1[j]), acc[2 * j + 1]);
                }
            }
        }

        // Reduce-scatter 32 ci over 64 lanes (co): 5 static butterfly steps.
        BSTEP(32, 16)
        BSTEP(16, 8)
        BSTEP(8, 4)
        BSTEP(4, 2)
        BSTEP(2, 1)
        float s = acc[0] + __shfl_xor(acc[0], 1, 64);
        if (!(lane & 1))
            compact[(size_t)i * CIN + (lane >> 1)] = s;   // 128B/point, coalesced
    }
}

// expand: dense sweep of the output grid. Per voxel g (layout-identical to
// idx): read idx[g]; load that point's compact row (or zeros); write all 32
// ci planes with coalesced stores. Every output line is written exactly once,
// full-width -> pure streaming-write roofline (~265MB write + ~27MB read).
__global__ __launch_bounds__(256) void expand_kernel(const int* __restrict__ idx,
                                                     const float* __restrict__ compact,
                                                     float* __restrict__ out) {
    const int HW    = H_ * W_;
    const int PLANE = D_ * HW;            // 1,036,521 elements per (b,ci) plane
    const int NVOX  = BATCH * PLANE;      // 2,073,042
    int g = blockIdx.x * 256 + threadIdx.x;
    if (g >= NVOX) return;

    int p   = idx[g];
    int b   = g / PLANE;
    int rem = g - b * PLANE;              // z*HW + y*W + x

    float r[CIN];
    if (p >= 0) {
        const float4* row = (const float4*)(compact + (size_t)p * CIN);
        #pragma unroll
        for (int q = 0; q < 8; ++q) {
            float4 v = row[q];
            r[4 * q + 0] = v.x; r[4 * q + 1] = v.y;
            r[4 * q + 2] = v.z; r[4 * q + 3] = v.w;
        }
    } else {
        #pragma unroll
        for (int q = 0; q < CIN; ++q) r[q] = 0.f;
    }

    float* o = out + (size_t)b * ((size_t)CIN * PLANE) + rem;
    #pragma unroll
    for (int ci = 0; ci < CIN; ++ci)
        __builtin_nontemporal_store(r[ci], o + (size_t)ci * PLANE);
}

extern "C" void kernel_launch(void* const* d_in, const int* in_sizes, int n_in,
                              void* d_out, int out_size, void* d_ws, size_t ws_size,
                              hipStream_t stream) {
    const float* feat  = (const float*)d_in[0];
    const int*   coors = (const int*)d_in[1];
    const float* w1    = (const float*)d_in[3];
    const float* w2    = (const float*)d_in[4];
    float*       out   = (float*)d_out;

    int n = in_sizes[0] / CIN;   // 150000 points total

    // Workspace: [idx 8.3MB][mid 64MB][w1p 110.6KB][w2p 110.6KB][compact 19.2MB]
    int*   idx      = (int*)d_ws;
    size_t idxBytes = (size_t)BATCH * D_ * H_ * W_ * sizeof(int);
    size_t midOff   = (idxBytes + 255) & ~(size_t)255;
    float* mid      = (float*)((char*)d_ws + midOff);
    size_t wOff     = midOff + (size_t)BATCH * MD * MH * MW * COUT * sizeof(float);
    wOff            = (wOff + 255) & ~(size_t)255;
    u32*   w1p      = (u32*)((char*)d_ws + wOff);
    u32*   w2p      = w1p + WLDS;
    float* compact  = (float*)(w2p + WLDS);   // 16B-aligned (wOff 256-aligned + 2*WLDS*4)

    (void)hipMemsetAsync(idx, 0xFF, idxBytes, stream);   // idx = -1
    // No dense-output memset: expand_kernel writes every output element
    // exactly once (zeros included), full-line coalesced.

    pack_kernel<<<(WLDS + 255) / 256, 256, 0, stream>>>(w1, w2, w1p, w2p);
    scatter_idx_kernel<<<(n + 255) / 256, 256, 0, stream>>>(coors, idx, n);

    mid_kernel<<<256, BLK, 0, stream>>>(feat, idx, w1p, mid);
    out_kernel<<<256, BLK, 0, stream>>>(coors, mid, w2p, compact, n);

    const int NVOX = BATCH * D_ * H_ * W_;
    expand_kernel<<<(NVOX + 255) / 256, 256, 0, stream>>>(idx, compact, out);
}